// Round 4
// baseline (245.313 us; speedup 1.0000x reference)
//
#include <hip/hip_runtime.h>
#include <math.h>
#include <stdint.h>

// tgate_hybrid: B=4,S=4096,DIMS=2048,T=10,K=2.
// R16: DIAGNOSTIC round. Five falsified theories (vmcnt coupling, load
// mechanism, NT, visit granularity, chip-wide interleave) were all built on
// an INFERRED k1 duration -- k1 has never appeared in the top-5 counter rows
// (cutoff ~77 us). This round prepends THREE pure-staging passes (identical
// 16-row x 2048-col gld_lds pattern, row base shifted +4096 rows = +32 MB to
// defeat L2 reuse, no VALU/MFMA attached, values never read; gld_lds has
// side effects so it cannot be DCE'd) to force k1 to ~4x duration -> #1 in
// top-5 WITH full counters. Dummy passes isolate pattern throughput from
// compute. Real pass is R14 verbatim -> absmax exactly 0.00390625.
// Predictions: L1 pattern-limited: k1 230-260us @ ~2.2 TB/s, VALUBusy<15%.
//              L2 stall-limited:   k1 120-140us @ ~4-4.5 TB/s.
//              L3 harness-floor:   k1  85-100us @ ~5.5-6.3 TB/s -> ROOFLINE.
//              FETCH << 520 MB -> MALL absorption, recalibrate.

#define NROWS   16384
#define DIMS_   2048
#define TT      10

typedef __attribute__((ext_vector_type(8))) short short8;
typedef __attribute__((ext_vector_type(4))) float f32x4;

__device__ __forceinline__ unsigned short bf16_rne(float f) {
    unsigned int u = __float_as_uint(f);
    unsigned int r = u + 0x7fffu + ((u >> 16) & 1u);
    return (unsigned short)(r >> 16);
}

// ---- k0: build B fragments (unchanged since R5; must stay identical).
__global__ __launch_bounds__(256)
void tgate_k0(const float* __restrict__ W_cls,
              const float* __restrict__ W_sparse,
              const float* __restrict__ W_gates,
              unsigned short* __restrict__ frag)
{
    int t = blockIdx.x * 256 + threadIdx.x;
    int K0   = t >> 7;
    int nt   = (t >> 6) & 1;
    int lane = t & 63;
    int n  = nt * 16 + (lane & 15);
    int kb = K0 * 32 + (lane >> 4) * 8;
    short8 hi, lo;
    #pragma unroll
    for (int j = 0; j < 8; ++j) {
        int k = kb + j;
        float w = 0.0f;
        if (n < 10)      w = W_cls[k * TT + n];
        else if (n < 20) w = W_sparse[k * TT + n - 10];
        else if (n < 30) w = W_gates[k * TT + n - 20];
        unsigned short h = bf16_rne(w);
        float back = __uint_as_float(((unsigned int)h) << 16);
        hi[j] = (short)h;
        lo[j] = (short)bf16_rne(w - back);
    }
    short8* fv = reinterpret_cast<short8*>(frag);
    fv[(K0 * 4 + nt * 2 + 0) * 64 + lane] = hi;
    fv[(K0 * 4 + nt * 2 + 1) * 64 + lane] = lo;
}

// stage one 16-row x 256-col chunk: 16 instrs, each 1 KB CONTIGUOUS within
// one x row (64 lanes x 16 B). LDS dest wave-uniform base + lane*16 ->
// row r lands at buf + r*260 .. +256 floats (pitch 260 for bank spread).
__device__ __forceinline__ void stage_span(const float* __restrict__ x,
                                           float* buf, int row0, int lane,
                                           int colf0)
{
    #pragma unroll
    for (int r = 0; r < 16; ++r) {
        const float* gp = x + (size_t)(row0 + r) * DIMS_ + colf0 + lane * 4;
        __builtin_amdgcn_global_load_lds(
            (const __attribute__((address_space(1))) void*)gp,
            (__attribute__((address_space(3))) void*)(buf + r * 260),
            16, 0, 0);
    }
}

// ---- k1: fused full-K MFMA GEMV + 3 diagnostic pure-staging passes
__global__ __launch_bounds__(256)
void tgate_k1(const float* __restrict__ x,
              const unsigned short* __restrict__ frag,
              const float* __restrict__ b_cls,
              const float* __restrict__ b_sparse,
              const float* __restrict__ b_gates,
              const float* __restrict__ alpha,
              float* __restrict__ out)
{
    // 4 waves x 16 rows x 260 floats = 66560 B; reused for red/fold (4752 f)
    __shared__ alignas(16) float smem[4 * 4160];

    const int tid   = threadIdx.x;
    const int lane  = tid & 63;
    const int wv    = __builtin_amdgcn_readfirstlane(tid >> 6);
    const int row0  = blockIdx.x * 16;
    const int m     = lane & 15;
    const int quad  = lane >> 4;
    const int cbase = wv * 512;          // wave's contiguous 512-col span

    float* buf = smem + wv * 4160;
    const short8* fv    = reinterpret_cast<const short8*>(frag);
    const short8* fbase = fv + (16 * wv * 4) * 64 + lane;   // step k -> +(k*4+j)*64

    // ==== DIAGNOSTIC: 3 pure-staging passes, same pattern, +32MB row shift,
    //      no compute attached. Measures the access pattern's raw throughput.
    #pragma unroll 1
    for (int p = 1; p <= 3; ++p) {
        const int rb = (row0 + p * 4096) & (NROWS - 1);   // stays 16-aligned
        stage_span(x, buf, rb, lane, cbase);
        __builtin_amdgcn_s_waitcnt(0x0F70);               // vmcnt(0)
        __builtin_amdgcn_sched_barrier(0);
        stage_span(x, buf, rb, lane, cbase + 256);
        __builtin_amdgcn_s_waitcnt(0x0F70);               // vmcnt(0)
        __builtin_amdgcn_sched_barrier(0);
    }
    // ==== end diagnostic; LDS content is garbage, fully overwritten below.

    f32x4 acc[2][2];
    #pragma unroll
    for (int h = 0; h < 2; ++h) {
        acc[h][0] = (f32x4){0.f, 0.f, 0.f, 0.f};
        acc[h][1] = (f32x4){0.f, 0.f, 0.f, 0.f};
    }

    // ---- stage chunk A (cols cbase..cbase+256) FIRST (oldest vmem ops)
    stage_span(x, buf, row0, lane, cbase);
    __builtin_amdgcn_sched_barrier(0);   // pin issue order: A before frag

    // frag prefetch for steps 0,1 (8 loads, L2-resident)
    short8 F[2][4];
    #pragma unroll
    for (int p = 0; p < 2; ++p) {
        #pragma unroll
        for (int j = 0; j < 4; ++j)
            F[p][j] = fbase[(p * 4 + j) * 64];
    }
    __builtin_amdgcn_sched_barrier(0);   // pin: frag issued after A, before wait

    // A fully landed when <=8 outstanding (the 8 frag loads)
    __builtin_amdgcn_s_waitcnt(0x0F78);  // vmcnt(8)
    __builtin_amdgcn_sched_barrier(0);   // no ds_read hoists above the wait

    #pragma unroll
    for (int k = 0; k < 16; ++k) {
        if (k == 8) {
            // all A ds_reads retired -> safe to overwrite buffer with B
            __builtin_amdgcn_s_waitcnt(0xC07F);  // lgkmcnt(0)
            __builtin_amdgcn_sched_barrier(0);
            stage_span(x, buf, row0, lane, cbase + 256);
            __builtin_amdgcn_s_waitcnt(0x0F70);  // vmcnt(0): B (+frag 8,9) landed
            __builtin_amdgcn_sched_barrier(0);
        }
        const int h = k >> 3;
        const float* src = buf + m * 260 + (k & 7) * 32 + quad * 8;
        float4 b0 = *reinterpret_cast<const float4*>(src);
        float4 b1 = *reinterpret_cast<const float4*>(src + 4);
        float f[8] = {b0.x, b0.y, b0.z, b0.w, b1.x, b1.y, b1.z, b1.w};
        short8 ah, al;
        #pragma unroll
        for (int j = 0; j < 8; ++j) {
            unsigned short hh = bf16_rne(f[j]);               // rne hi (R5.. path)
            float back = __uint_as_float(((unsigned int)hh) << 16);
            ah[j] = (short)hh;
            al[j] = (short)bf16_rne(f[j] - back);
        }
        short8 h0 = F[k & 1][0], l0 = F[k & 1][1];
        short8 h1 = F[k & 1][2], l1 = F[k & 1][3];

        acc[h][0] = __builtin_amdgcn_mfma_f32_16x16x32_bf16(ah, h0, acc[h][0], 0, 0, 0);
        acc[h][0] = __builtin_amdgcn_mfma_f32_16x16x32_bf16(al, h0, acc[h][0], 0, 0, 0);
        acc[h][0] = __builtin_amdgcn_mfma_f32_16x16x32_bf16(ah, l0, acc[h][0], 0, 0, 0);
        acc[h][1] = __builtin_amdgcn_mfma_f32_16x16x32_bf16(ah, h1, acc[h][1], 0, 0, 0);
        acc[h][1] = __builtin_amdgcn_mfma_f32_16x16x32_bf16(al, h1, acc[h][1], 0, 0, 0);
        acc[h][1] = __builtin_amdgcn_mfma_f32_16x16x32_bf16(ah, l1, acc[h][1], 0, 0, 0);

        if (k + 2 < 16) {                 // refill frag slot (k&1) for step k+2
            #pragma unroll
            for (int j = 0; j < 4; ++j)
                F[k & 1][j] = fbase[((k + 2) * 4 + j) * 64];
        }
    }

    // ---- partials to LDS: red[s][row][j], pitch 33 (verbatim since R5;
    //      red aliases the staging buffer, valid after the barrier)
    float* red = smem;
    __syncthreads();
    #pragma unroll
    for (int h = 0; h < 2; ++h) {
        int s = 2 * wv + h;
        #pragma unroll
        for (int r = 0; r < 4; ++r) {
            int row = quad * 4 + r;       // C/D layout (verified m89)
            red[(s * 16 + row) * 33 + m]      = acc[h][0][r];
            red[(s * 16 + row) * 33 + m + 16] = acc[h][1][r];
        }
    }
    __syncthreads();

    // ---- fold: bit-identical (l=0; s=0..7 ascending)
    float* fold = red + 8 * 16 * 33;
    #pragma unroll
    for (int u = 0; u < 2; ++u) {
        int i = tid * 2 + u;
        int row = i >> 5, j = i & 31;
        float a = 0.0f;
        #pragma unroll
        for (int s = 0; s < 8; ++s) a += red[(s * 16 + row) * 33 + j];
        fold[row * 33 + j] = a;
    }
    __syncthreads();

    // ---- epilogue: lanes 0..15 of wave 0 (verbatim since R5)
    if (tid < 16) {
        const float* l = &fold[tid * 33];
        float lc[TT], lsp[TT], g[TT];
        #pragma unroll
        for (int t = 0; t < TT; ++t) {
            lc[t]  = l[t]      + b_cls[t];
            lsp[t] = l[10 + t] + b_sparse[t];
            float lg = l[20 + t] + b_gates[t];
            g[t] = 1.0f / (1.0f + __expf(-lg));
        }
        float mm = lc[0];
        #pragma unroll
        for (int t = 1; t < TT; ++t) mm = fmaxf(mm, lc[t]);
        float esum = 0.0f, gdot = 0.0f;
        #pragma unroll
        for (int t = 0; t < TT; ++t) {
            float e = __expf(lc[t] - mm);
            esum += e;
            gdot = fmaf(g[t], e, gdot);
        }
        float v1 = lsp[0], v2 = -1e30f, gv1 = g[0], gv2 = 0.0f;
        #pragma unroll
        for (int t = 1; t < TT; ++t) {
            if (lsp[t] > v1)      { v2 = v1; gv2 = gv1; v1 = lsp[t]; gv1 = g[t]; }
            else if (lsp[t] > v2) { v2 = lsp[t]; gv2 = g[t]; }
        }
        float s1 = 1.0f / (1.0f + __expf(v2 - v1));
        float s2 = 1.0f - s1;
        float a  = 1.0f / (1.0f + __expf(-alpha[0]));
        float sparse_dot = fmaf(gv1, s1, gv2 * s2);
        out[row0 + tid] = fmaf(a, sparse_dot, (1.0f - a) * (gdot / esum));
    }
}

extern "C" void kernel_launch(void* const* d_in, const int* in_sizes, int n_in,
                              void* d_out, int out_size, void* d_ws, size_t ws_size,
                              hipStream_t stream) {
    const float* x        = (const float*)d_in[0];
    const float* W_cls    = (const float*)d_in[1];
    const float* b_cls    = (const float*)d_in[2];
    const float* W_sparse = (const float*)d_in[3];
    const float* b_sparse = (const float*)d_in[4];
    const float* W_gates  = (const float*)d_in[5];
    const float* b_gates  = (const float*)d_in[6];
    const float* alpha    = (const float*)d_in[7];
    float* out = (float*)d_out;

    unsigned short* frag = (unsigned short*)d_ws;   // 256 KB

    tgate_k0<<<dim3(32), dim3(256), 0, stream>>>(W_cls, W_sparse, W_gates, frag);
    tgate_k1<<<dim3(NROWS / 16), dim3(256), 0, stream>>>(x, frag, b_cls, b_sparse,
                                                         b_gates, alpha, out);
}

// Round 5
// 211.596 us; speedup vs baseline: 1.1593x; 1.1593x over previous
//
#include <hip/hip_runtime.h>
#include <math.h>
#include <stdint.h>

// tgate_hybrid: B=4,S=4096,DIMS=2048,T=10,K=2.
// R17: channel-parity fix. R16 diagnostic resolved the plateau: warm
// (L3-served) staging runs at ~11 TB/s -> the instruction pattern is fine;
// only COLD HBM reads run at ~2.5 TB/s (real pass ~56 us). Surviving
// theory: instantaneous footprint aliasing. Chunk A had all 4 waves reading
// 1KB granules {0,2,4,6} of each 8KB row -> addr bit 10 == 0 for every
// in-flight byte -> half the HBM channels idle per chunk phase (~50% BW).
// Fix: odd waves stage granule 1 first (chunk-A granules {0,3,4,7}, bits
// 10/11/12 balanced; chunk-B {1,2,5,6} balanced). Odd waves compute k=8..15
// first (acc[1]) then k=0..7 (acc[0]): each accumulator still sums its own
// 8 k-steps in ascending order with the identical 6-MFMA sequence ->
// per-accumulator values bit-identical -> absmax exactly 0.00390625.
// KOFS is a template param under a wave-uniform branch (no runtime-indexed
// register arrays). Everything else is R14 verbatim.

#define NROWS   16384
#define DIMS_   2048
#define TT      10

typedef __attribute__((ext_vector_type(8))) short short8;
typedef __attribute__((ext_vector_type(4))) float f32x4;

__device__ __forceinline__ unsigned short bf16_rne(float f) {
    unsigned int u = __float_as_uint(f);
    unsigned int r = u + 0x7fffu + ((u >> 16) & 1u);
    return (unsigned short)(r >> 16);
}

// ---- k0: build B fragments (unchanged since R5; must stay identical).
__global__ __launch_bounds__(256)
void tgate_k0(const float* __restrict__ W_cls,
              const float* __restrict__ W_sparse,
              const float* __restrict__ W_gates,
              unsigned short* __restrict__ frag)
{
    int t = blockIdx.x * 256 + threadIdx.x;
    int K0   = t >> 7;
    int nt   = (t >> 6) & 1;
    int lane = t & 63;
    int n  = nt * 16 + (lane & 15);
    int kb = K0 * 32 + (lane >> 4) * 8;
    short8 hi, lo;
    #pragma unroll
    for (int j = 0; j < 8; ++j) {
        int k = kb + j;
        float w = 0.0f;
        if (n < 10)      w = W_cls[k * TT + n];
        else if (n < 20) w = W_sparse[k * TT + n - 10];
        else if (n < 30) w = W_gates[k * TT + n - 20];
        unsigned short h = bf16_rne(w);
        float back = __uint_as_float(((unsigned int)h) << 16);
        hi[j] = (short)h;
        lo[j] = (short)bf16_rne(w - back);
    }
    short8* fv = reinterpret_cast<short8*>(frag);
    fv[(K0 * 4 + nt * 2 + 0) * 64 + lane] = hi;
    fv[(K0 * 4 + nt * 2 + 1) * 64 + lane] = lo;
}

// stage one 16-row x 256-col chunk: 16 instrs, each 1 KB CONTIGUOUS within
// one x row (64 lanes x 16 B). LDS dest wave-uniform base + lane*16 ->
// row r lands at buf + r*260 .. +256 floats (pitch 260 for bank spread).
__device__ __forceinline__ void stage_span(const float* __restrict__ x,
                                           float* buf, int row0, int lane,
                                           int colf0)
{
    #pragma unroll
    for (int r = 0; r < 16; ++r) {
        const float* gp = x + (size_t)(row0 + r) * DIMS_ + colf0 + lane * 4;
        __builtin_amdgcn_global_load_lds(
            (const __attribute__((address_space(1))) void*)gp,
            (__attribute__((address_space(3))) void*)(buf + r * 260),
            16, 0, 0);
    }
}

// 16 k-steps, staged-chunk order parameterized by KOFS (0: k=0..15;
// 8: k=8..15 then 0..7). acc/h indices are compile-time after unroll.
template<int KOFS>
__device__ __forceinline__ void kloop16(const float* __restrict__ x,
                                        float* buf,
                                        const short8* fbase,
                                        int row0, int lane, int m, int quad,
                                        int cbase,
                                        f32x4 (&acc)[2][2],
                                        short8 (&F)[2][4])
{
    #pragma unroll
    for (int c = 0; c < 16; ++c) {
        if (c == 8) {
            // all first-chunk ds_reads retired -> safe to overwrite buffer
            __builtin_amdgcn_s_waitcnt(0xC07F);  // lgkmcnt(0)
            __builtin_amdgcn_sched_barrier(0);
            stage_span(x, buf, row0, lane, cbase + (KOFS ? 0 : 256));
            __builtin_amdgcn_s_waitcnt(0x0F70);  // vmcnt(0): chunk2 (+frags) landed
            __builtin_amdgcn_sched_barrier(0);
        }
        const int k = (c + KOFS) & 15;       // compile-time
        const int h = k >> 3;                // compile-time
        const float* src = buf + m * 260 + (c & 7) * 32 + quad * 8;
        float4 b0 = *reinterpret_cast<const float4*>(src);
        float4 b1 = *reinterpret_cast<const float4*>(src + 4);
        float f[8] = {b0.x, b0.y, b0.z, b0.w, b1.x, b1.y, b1.z, b1.w};
        short8 ah, al;
        #pragma unroll
        for (int j = 0; j < 8; ++j) {
            unsigned short hh = bf16_rne(f[j]);               // rne hi (R5.. path)
            float back = __uint_as_float(((unsigned int)hh) << 16);
            ah[j] = (short)hh;
            al[j] = (short)bf16_rne(f[j] - back);
        }
        short8 h0 = F[c & 1][0], l0 = F[c & 1][1];
        short8 h1 = F[c & 1][2], l1 = F[c & 1][3];

        acc[h][0] = __builtin_amdgcn_mfma_f32_16x16x32_bf16(ah, h0, acc[h][0], 0, 0, 0);
        acc[h][0] = __builtin_amdgcn_mfma_f32_16x16x32_bf16(al, h0, acc[h][0], 0, 0, 0);
        acc[h][0] = __builtin_amdgcn_mfma_f32_16x16x32_bf16(ah, l0, acc[h][0], 0, 0, 0);
        acc[h][1] = __builtin_amdgcn_mfma_f32_16x16x32_bf16(ah, h1, acc[h][1], 0, 0, 0);
        acc[h][1] = __builtin_amdgcn_mfma_f32_16x16x32_bf16(al, h1, acc[h][1], 0, 0, 0);
        acc[h][1] = __builtin_amdgcn_mfma_f32_16x16x32_bf16(ah, l1, acc[h][1], 0, 0, 0);

        if (c + 2 < 16) {                 // refill frag slot (c&1) for step c+2
            const int kn = (c + 2 + KOFS) & 15;
            #pragma unroll
            for (int j = 0; j < 4; ++j)
                F[c & 1][j] = fbase[(kn * 4 + j) * 64];
        }
    }
}

// ---- k1: fused full-K MFMA GEMV, channel-parity-balanced LDS staging
__global__ __launch_bounds__(256)
void tgate_k1(const float* __restrict__ x,
              const unsigned short* __restrict__ frag,
              const float* __restrict__ b_cls,
              const float* __restrict__ b_sparse,
              const float* __restrict__ b_gates,
              const float* __restrict__ alpha,
              float* __restrict__ out)
{
    // 4 waves x 16 rows x 260 floats = 66560 B; reused for red/fold (4752 f)
    __shared__ alignas(16) float smem[4 * 4160];

    const int tid   = threadIdx.x;
    const int lane  = tid & 63;
    const int wv    = __builtin_amdgcn_readfirstlane(tid >> 6);
    const int row0  = blockIdx.x * 16;
    const int m     = lane & 15;
    const int quad  = lane >> 4;
    const int cbase = wv * 512;          // wave's contiguous 512-col span
    const int par   = wv & 1;            // chunk-parity swap for odd waves
    const int kofs  = par << 3;

    float* buf = smem + wv * 4160;
    const short8* fv    = reinterpret_cast<const short8*>(frag);
    const short8* fbase = fv + (16 * wv * 4) * 64 + lane;   // step k -> +(k*4+j)*64

    f32x4 acc[2][2];
    #pragma unroll
    for (int h = 0; h < 2; ++h) {
        acc[h][0] = (f32x4){0.f, 0.f, 0.f, 0.f};
        acc[h][1] = (f32x4){0.f, 0.f, 0.f, 0.f};
    }

    // ---- stage first chunk (granule `par` of the wave's 2KB span) FIRST
    stage_span(x, buf, row0, lane, cbase + par * 256);
    __builtin_amdgcn_sched_barrier(0);   // pin issue order: stage before frag

    // frag prefetch for the first two k-steps of this wave's order
    short8 F[2][4];
    #pragma unroll
    for (int p = 0; p < 2; ++p) {
        #pragma unroll
        for (int j = 0; j < 4; ++j)
            F[p][j] = fbase[((((p + kofs) & 15)) * 4 + j) * 64];
    }
    __builtin_amdgcn_sched_barrier(0);   // pin: frag issued after stage, before wait

    // first chunk fully landed when <=8 outstanding (the 8 frag loads)
    __builtin_amdgcn_s_waitcnt(0x0F78);  // vmcnt(8)
    __builtin_amdgcn_sched_barrier(0);   // no ds_read hoists above the wait

    if (par) kloop16<8>(x, buf, fbase, row0, lane, m, quad, cbase, acc, F);
    else     kloop16<0>(x, buf, fbase, row0, lane, m, quad, cbase, acc, F);

    // ---- partials to LDS: red[s][row][j], pitch 33 (verbatim since R5;
    //      red aliases the staging buffer, valid after the barrier)
    float* red = smem;
    __syncthreads();
    #pragma unroll
    for (int h = 0; h < 2; ++h) {
        int s = 2 * wv + h;
        #pragma unroll
        for (int r = 0; r < 4; ++r) {
            int row = quad * 4 + r;       // C/D layout (verified m89)
            red[(s * 16 + row) * 33 + m]      = acc[h][0][r];
            red[(s * 16 + row) * 33 + m + 16] = acc[h][1][r];
        }
    }
    __syncthreads();

    // ---- fold: bit-identical (l=0; s=0..7 ascending)
    float* fold = red + 8 * 16 * 33;
    #pragma unroll
    for (int u = 0; u < 2; ++u) {
        int i = tid * 2 + u;
        int row = i >> 5, j = i & 31;
        float a = 0.0f;
        #pragma unroll
        for (int s = 0; s < 8; ++s) a += red[(s * 16 + row) * 33 + j];
        fold[row * 33 + j] = a;
    }
    __syncthreads();

    // ---- epilogue: lanes 0..15 of wave 0 (verbatim since R5)
    if (tid < 16) {
        const float* l = &fold[tid * 33];
        float lc[TT], lsp[TT], g[TT];
        #pragma unroll
        for (int t = 0; t < TT; ++t) {
            lc[t]  = l[t]      + b_cls[t];
            lsp[t] = l[10 + t] + b_sparse[t];
            float lg = l[20 + t] + b_gates[t];
            g[t] = 1.0f / (1.0f + __expf(-lg));
        }
        float mm = lc[0];
        #pragma unroll
        for (int t = 1; t < TT; ++t) mm = fmaxf(mm, lc[t]);
        float esum = 0.0f, gdot = 0.0f;
        #pragma unroll
        for (int t = 0; t < TT; ++t) {
            float e = __expf(lc[t] - mm);
            esum += e;
            gdot = fmaf(g[t], e, gdot);
        }
        float v1 = lsp[0], v2 = -1e30f, gv1 = g[0], gv2 = 0.0f;
        #pragma unroll
        for (int t = 1; t < TT; ++t) {
            if (lsp[t] > v1)      { v2 = v1; gv2 = gv1; v1 = lsp[t]; gv1 = g[t]; }
            else if (lsp[t] > v2) { v2 = lsp[t]; gv2 = g[t]; }
        }
        float s1 = 1.0f / (1.0f + __expf(v2 - v1));
        float s2 = 1.0f - s1;
        float a  = 1.0f / (1.0f + __expf(-alpha[0]));
        float sparse_dot = fmaf(gv1, s1, gv2 * s2);
        out[row0 + tid] = fmaf(a, sparse_dot, (1.0f - a) * (gdot / esum));
    }
}

extern "C" void kernel_launch(void* const* d_in, const int* in_sizes, int n_in,
                              void* d_out, int out_size, void* d_ws, size_t ws_size,
                              hipStream_t stream) {
    const float* x        = (const float*)d_in[0];
    const float* W_cls    = (const float*)d_in[1];
    const float* b_cls    = (const float*)d_in[2];
    const float* W_sparse = (const float*)d_in[3];
    const float* b_sparse = (const float*)d_in[4];
    const float* W_gates  = (const float*)d_in[5];
    const float* b_gates  = (const float*)d_in[6];
    const float* alpha    = (const float*)d_in[7];
    float* out = (float*)d_out;

    unsigned short* frag = (unsigned short*)d_ws;   // 256 KB

    tgate_k0<<<dim3(32), dim3(256), 0, stream>>>(W_cls, W_sparse, W_gates, frag);
    tgate_k1<<<dim3(NROWS / 16), dim3(256), 0, stream>>>(x, frag, b_cls, b_sparse,
                                                         b_gates, alpha, out);
}

// Round 6
// 210.949 us; speedup vs baseline: 1.1629x; 1.0031x over previous
//
#include <hip/hip_runtime.h>
#include <math.h>
#include <stdint.h>

// tgate_hybrid: B=4,S=4096,DIMS=2048,T=10,K=2.
// R18: duty-cycle fix. R17's counters (first ever for k1): 83us, FETCH 67MB,
// MfmaUtil 2.9%, VALUBusy 8.6%, occupancy 19.7%, conflicts ~0 -> NOTHING
// saturated; k1 is stall-limited. R16 showed the same gld_lds instructions
// back-to-back (no compute between bursts) stream at ~11 TB/s. Difference:
// the real kernel alternates burst -> FULL drain (vmcnt(8)/vmcnt(0)) ->
// compute, in near-lockstep across ~1600 resident waves -> chip-wide memory
// idle windows -> ~1.6-2.4 TB/s effective, mechanism-independent (explains
// R12..R17 convergence). Fix: 4-deep chunk pipeline (chunk = 16 rows x 64
// cols = 4 KB, R12's verified 4-instr/260-pitch layout), counted waits
// {12,20,28,36,36,32,28,24} derived from a sched_barrier-pinned issue
// timeline; frags issued BEFORE the staging chunks they precede, so every
// wait (manual or compiler) targets OLD ops -- in-order vmcnt retirement
// then never drains the young staging chunks (R13's actual failure mode).
// Data values, k-order, 6-MFMA sequence, fold, epilogue bit-identical to
// R12/R14 -> absmax must remain exactly 0.00390625.

#define NROWS   16384
#define DIMS_   2048
#define TT      10

// s_waitcnt simm16 encodings: vmcnt in [3:0]+[15:14], expcnt=7 (no wait),
// lgkmcnt=15 (no wait) unless noted.
#define WV12  0x0F7C   // vmcnt(12)
#define WV20  0x4F74   // vmcnt(20)
#define WV24  0x4F78   // vmcnt(24)
#define WV28  0x4F7C   // vmcnt(28)
#define WV32  0x8F70   // vmcnt(32)
#define WV36  0x8F74   // vmcnt(36)
#define WLGKM0 0xC07F  // lgkmcnt(0), vmcnt/exp no-wait

typedef __attribute__((ext_vector_type(8))) short short8;
typedef __attribute__((ext_vector_type(4))) float f32x4;

__device__ __forceinline__ unsigned short bf16_rne(float f) {
    unsigned int u = __float_as_uint(f);
    unsigned int r = u + 0x7fffu + ((u >> 16) & 1u);
    return (unsigned short)(r >> 16);
}

// ---- k0: build B fragments (unchanged since R5; must stay identical).
__global__ __launch_bounds__(256)
void tgate_k0(const float* __restrict__ W_cls,
              const float* __restrict__ W_sparse,
              const float* __restrict__ W_gates,
              unsigned short* __restrict__ frag)
{
    int t = blockIdx.x * 256 + threadIdx.x;
    int K0   = t >> 7;
    int nt   = (t >> 6) & 1;
    int lane = t & 63;
    int n  = nt * 16 + (lane & 15);
    int kb = K0 * 32 + (lane >> 4) * 8;
    short8 hi, lo;
    #pragma unroll
    for (int j = 0; j < 8; ++j) {
        int k = kb + j;
        float w = 0.0f;
        if (n < 10)      w = W_cls[k * TT + n];
        else if (n < 20) w = W_sparse[k * TT + n - 10];
        else if (n < 30) w = W_gates[k * TT + n - 20];
        unsigned short h = bf16_rne(w);
        float back = __uint_as_float(((unsigned int)h) << 16);
        hi[j] = (short)h;
        lo[j] = (short)bf16_rne(w - back);
    }
    short8* fv = reinterpret_cast<short8*>(frag);
    fv[(K0 * 4 + nt * 2 + 0) * 64 + lane] = hi;
    fv[(K0 * 4 + nt * 2 + 1) * 64 + lane] = lo;
}

// one chunk: 16 rows x 64 cols = 4 KB via 4 async 1-KB instrs (4 rows each),
// LDS layout: instr t -> bufbase + t*260 floats (R12's verified layout:
// global row row0 + 4t + (lane>>4), cols colf0 + (lane&15)*4).
__device__ __forceinline__ void issue_chunk(const float* __restrict__ x,
                                            float* bufbase, int row0, int lane,
                                            int colf0)
{
    #pragma unroll
    for (int t = 0; t < 4; ++t) {
        const float* gp = x + (size_t)(row0 + 4 * t + (lane >> 4)) * DIMS_
                            + colf0 + (lane & 15) * 4;
        __builtin_amdgcn_global_load_lds(
            (const __attribute__((address_space(1))) void*)gp,
            (__attribute__((address_space(3))) void*)(bufbase + t * 260),
            16, 0, 0);
    }
}

// two k-steps (k = 2C, 2C+1) from one chunk buffer; exact R12 FP path.
// Refills frag slot for step k+2 (1-iteration prefetch distance).
template<int C>
__device__ __forceinline__ void step_pair(const float* Lbuf,
                                          const short8* fbase,
                                          int m, int quad,
                                          f32x4 (&acc)[2][2],
                                          short8 (&F)[2][4])
{
    #pragma unroll
    for (int u = 0; u < 2; ++u) {
        const int k = 2 * C + u;          // compile-time
        const int h = k >> 3;             // compile-time
        const float* src = Lbuf + (m >> 2) * 260 + (m & 3) * 64 + u * 32 + quad * 8;
        float4 b0 = *reinterpret_cast<const float4*>(src);
        float4 b1 = *reinterpret_cast<const float4*>(src + 4);
        float f[8] = {b0.x, b0.y, b0.z, b0.w, b1.x, b1.y, b1.z, b1.w};
        short8 ah, al;
        #pragma unroll
        for (int j = 0; j < 8; ++j) {
            unsigned short hh = bf16_rne(f[j]);               // rne hi (R5.. path)
            float back = __uint_as_float(((unsigned int)hh) << 16);
            ah[j] = (short)hh;
            al[j] = (short)bf16_rne(f[j] - back);
        }
        short8 h0 = F[u][0], l0 = F[u][1], h1 = F[u][2], l1 = F[u][3];

        acc[h][0] = __builtin_amdgcn_mfma_f32_16x16x32_bf16(ah, h0, acc[h][0], 0, 0, 0);
        acc[h][0] = __builtin_amdgcn_mfma_f32_16x16x32_bf16(al, h0, acc[h][0], 0, 0, 0);
        acc[h][0] = __builtin_amdgcn_mfma_f32_16x16x32_bf16(ah, l0, acc[h][0], 0, 0, 0);
        acc[h][1] = __builtin_amdgcn_mfma_f32_16x16x32_bf16(ah, h1, acc[h][1], 0, 0, 0);
        acc[h][1] = __builtin_amdgcn_mfma_f32_16x16x32_bf16(al, h1, acc[h][1], 0, 0, 0);
        acc[h][1] = __builtin_amdgcn_mfma_f32_16x16x32_bf16(ah, l1, acc[h][1], 0, 0, 0);

        if (k + 2 < 16) {                 // refill same slot for step k+2
            #pragma unroll
            for (int j = 0; j < 4; ++j)
                F[u][j] = fbase[((k + 2) * 4 + j) * 64];
        }
    }
}

// ---- k1: fused full-K MFMA GEMV, 4-deep always-outstanding chunk pipeline
__global__ __launch_bounds__(256)
void tgate_k1(const float* __restrict__ x,
              const unsigned short* __restrict__ frag,
              const float* __restrict__ b_cls,
              const float* __restrict__ b_sparse,
              const float* __restrict__ b_gates,
              const float* __restrict__ alpha,
              float* __restrict__ out)
{
    // 4 waves x 4 bufs x 1040 floats = 66560 B; reused for red/fold (4752 f)
    __shared__ alignas(16) float smem[4 * 4160];

    const int tid   = threadIdx.x;
    const int lane  = tid & 63;
    const int wv    = __builtin_amdgcn_readfirstlane(tid >> 6);
    const int row0  = blockIdx.x * 16;
    const int m     = lane & 15;
    const int quad  = lane >> 4;
    const int cbase = wv * 512;          // wave's contiguous 512-col span

    float* bufs = smem + wv * 4160;      // buffer b at bufs + b*1040
    const short8* fv    = reinterpret_cast<const short8*>(frag);
    const short8* fbase = fv + (16 * wv * 4) * 64 + lane;   // step k -> +(k*4+j)*64

    f32x4 acc[2][2];
    #pragma unroll
    for (int h = 0; h < 2; ++h) {
        acc[h][0] = (f32x4){0.f, 0.f, 0.f, 0.f};
        acc[h][1] = (f32x4){0.f, 0.f, 0.f, 0.f};
    }

    // ---- prologue: frags FIRST (so they are always older than staging),
    //      then chunks 0..3. Order pinned.
    short8 F[2][4];
    #pragma unroll
    for (int p = 0; p < 2; ++p) {
        #pragma unroll
        for (int j = 0; j < 4; ++j)
            F[p][j] = fbase[(p * 4 + j) * 64];
    }
    __builtin_amdgcn_sched_barrier(0);
    issue_chunk(x, bufs + 0 * 1040, row0, lane, cbase + 0 * 64);
    issue_chunk(x, bufs + 1 * 1040, row0, lane, cbase + 1 * 64);
    issue_chunk(x, bufs + 2 * 1040, row0, lane, cbase + 2 * 64);
    issue_chunk(x, bufs + 3 * 1040, row0, lane, cbase + 3 * 64);
    __builtin_amdgcn_sched_barrier(0);

    // ---- 8 iterations, 2 k-steps each. Wait counts = #vmem ops younger
    //      than the awaited chunk in the pinned issue timeline (safe:
    //      under-counting only over-waits). Stage segment re-arms buffer
    //      (c&3) with chunk c+4 after lgkmcnt(0) (ds_reads retired).
    #define KITER(c, WCODE, DO_STAGE)                                        \
    {                                                                        \
        __builtin_amdgcn_s_waitcnt(WCODE);                                   \
        __builtin_amdgcn_sched_barrier(0);                                   \
        step_pair<c>(bufs + ((c) & 3) * 1040, fbase, m, quad, acc, F);       \
        __builtin_amdgcn_sched_barrier(0);                                   \
        if (DO_STAGE) {                                                      \
            __builtin_amdgcn_s_waitcnt(WLGKM0);                              \
            __builtin_amdgcn_sched_barrier(0);                               \
            issue_chunk(x, bufs + ((c) & 3) * 1040, row0, lane,              \
                        cbase + ((c) + 4) * 64);                             \
            __builtin_amdgcn_sched_barrier(0);                               \
        }                                                                    \
    }

    KITER(0, WV12, 1)
    KITER(1, WV20, 1)
    KITER(2, WV28, 1)
    KITER(3, WV36, 1)
    KITER(4, WV36, 0)
    KITER(5, WV32, 0)
    KITER(6, WV28, 0)
    KITER(7, WV24, 0)
    #undef KITER

    // ---- partials to LDS: red[s][row][j], pitch 33 (verbatim since R5;
    //      red aliases the staging buffers, valid after the barrier)
    float* red = smem;
    __syncthreads();
    #pragma unroll
    for (int h = 0; h < 2; ++h) {
        int s = 2 * wv + h;
        #pragma unroll
        for (int r = 0; r < 4; ++r) {
            int row = quad * 4 + r;       // C/D layout (verified m89)
            red[(s * 16 + row) * 33 + m]      = acc[h][0][r];
            red[(s * 16 + row) * 33 + m + 16] = acc[h][1][r];
        }
    }
    __syncthreads();

    // ---- fold: bit-identical (l=0; s=0..7 ascending)
    float* fold = red + 8 * 16 * 33;
    #pragma unroll
    for (int u = 0; u < 2; ++u) {
        int i = tid * 2 + u;
        int row = i >> 5, j = i & 31;
        float a = 0.0f;
        #pragma unroll
        for (int s = 0; s < 8; ++s) a += red[(s * 16 + row) * 33 + j];
        fold[row * 33 + j] = a;
    }
    __syncthreads();

    // ---- epilogue: lanes 0..15 of wave 0 (verbatim since R5)
    if (tid < 16) {
        const float* l = &fold[tid * 33];
        float lc[TT], lsp[TT], g[TT];
        #pragma unroll
        for (int t = 0; t < TT; ++t) {
            lc[t]  = l[t]      + b_cls[t];
            lsp[t] = l[10 + t] + b_sparse[t];
            float lg = l[20 + t] + b_gates[t];
            g[t] = 1.0f / (1.0f + __expf(-lg));
        }
        float mm = lc[0];
        #pragma unroll
        for (int t = 1; t < TT; ++t) mm = fmaxf(mm, lc[t]);
        float esum = 0.0f, gdot = 0.0f;
        #pragma unroll
        for (int t = 0; t < TT; ++t) {
            float e = __expf(lc[t] - mm);
            esum += e;
            gdot = fmaf(g[t], e, gdot);
        }
        float v1 = lsp[0], v2 = -1e30f, gv1 = g[0], gv2 = 0.0f;
        #pragma unroll
        for (int t = 1; t < TT; ++t) {
            if (lsp[t] > v1)      { v2 = v1; gv2 = gv1; v1 = lsp[t]; gv1 = g[t]; }
            else if (lsp[t] > v2) { v2 = lsp[t]; gv2 = g[t]; }
        }
        float s1 = 1.0f / (1.0f + __expf(v2 - v1));
        float s2 = 1.0f - s1;
        float a  = 1.0f / (1.0f + __expf(-alpha[0]));
        float sparse_dot = fmaf(gv1, s1, gv2 * s2);
        out[row0 + tid] = fmaf(a, sparse_dot, (1.0f - a) * (gdot / esum));
    }
}

extern "C" void kernel_launch(void* const* d_in, const int* in_sizes, int n_in,
                              void* d_out, int out_size, void* d_ws, size_t ws_size,
                              hipStream_t stream) {
    const float* x        = (const float*)d_in[0];
    const float* W_cls    = (const float*)d_in[1];
    const float* b_cls    = (const float*)d_in[2];
    const float* W_sparse = (const float*)d_in[3];
    const float* b_sparse = (const float*)d_in[4];
    const float* W_gates  = (const float*)d_in[5];
    const float* b_gates  = (const float*)d_in[6];
    const float* alpha    = (const float*)d_in[7];
    float* out = (float*)d_out;

    unsigned short* frag = (unsigned short*)d_ws;   // 256 KB

    tgate_k0<<<dim3(32), dim3(256), 0, stream>>>(W_cls, W_sparse, W_gates, frag);
    tgate_k1<<<dim3(NROWS / 16), dim3(256), 0, stream>>>(x, frag, b_cls, b_sparse,
                                                         b_gates, alpha, out);
}